// Round 1
// baseline (36268.570 us; speedup 1.0000x reference)
//
#include <hip/hip_runtime.h>
#include <cmath>

constexpr int kB = 32, kS = 32, kE = 512, kH = 8, kV = 10000, kNB = 4;

// ---------------- device scratch (avoids ws_size uncertainty) ----------------
__device__ float g_w[kB * kS];
__device__ float g_pe[kS * kE];
__device__ float g_Y[kB * kS * kE];
__device__ float g_act[kB * kS * kE];
__device__ float g_qkv[kB * kS * 3 * kE];
__device__ float g_attn[kB * kS * kE];
__device__ float g_tmp[kB * kS * kE];
__device__ float g_h[kB * kS * kE];
__device__ float g_h2[kB * kS * kE];
__device__ float g_ff[kB * kS * kE];
__device__ float g_om[kB * kS * kH];
__device__ float g_logits[kB * kV];
__device__ float g_U[kNB * kE * kH];
__device__ float g_a0[kNB * kH];
__device__ float g_G[kNB * kH * kE];
__device__ float g_c0[kNB * kE];

// ---------------- helpers ----------------
__device__ __forceinline__ float block_reduce_sum(float v, float* red) {
#pragma unroll
    for (int o = 32; o > 0; o >>= 1) v += __shfl_xor(v, o);
    int wid = threadIdx.x >> 6;
    if ((threadIdx.x & 63) == 0) red[wid] = v;
    __syncthreads();
    v = red[0] + red[1] + red[2] + red[3];
    __syncthreads();
    return v;
}

// ---------------- setup kernels ----------------
__global__ void onehot_k(float* __restrict__ out) {
    int i = blockIdx.x * 256 + threadIdx.x;
    if (i >= kB * kV) return;
    int b = i / kV, v = i - b * kV;
    out[(size_t)b * kS * kV + v] = (v == 0) ? 1.f : 0.f;
}

__global__ void pe_k(float* __restrict__ pe) {
    int i = blockIdx.x * 256 + threadIdx.x;  // < kS*kE
    int s = i >> 9, e = i & 511;
    int base = e & ~1;
    float div = expf((float)base * (-logf(10000.f) / (float)kE));
    float ang = (float)s * div;
    pe[i] = (e & 1) ? cosf(ang) : sinf(ang);
}

__global__ void compute_w_k(const float* __restrict__ noise, const float* __restrict__ W_in,
                            const float* __restrict__ b_in, float* __restrict__ w) {
    __shared__ float X[kB * kS], T[kB * kS];
    int tid = threadIdx.x;  // 1024
    X[tid] = noise[tid];
    __syncthreads();
    int r = tid >> 5, c = tid & 31;
    float acc = b_in[c];
    for (int k = 0; k < 32; ++k) acc = fmaf(X[r * 32 + k], W_in[k * 32 + c], acc);
    T[tid] = acc;
    __syncthreads();
    acc = b_in[32 + c];
    for (int k = 0; k < 32; ++k) acc = fmaf(T[r * 32 + k], W_in[1024 + k * 32 + c], acc);
    w[tid] = acc;
}

__global__ void initY_k(const float* __restrict__ emb, const float* __restrict__ pe,
                        float* __restrict__ Y) {
    int i = blockIdx.x * 256 + threadIdx.x;  // < kB*kE
    int b = i >> 9, e = i & 511;
    Y[(size_t)b * kS * kE + e] = emb[e] + pe[e];
}

// Precompute per-block cross-attn reduced operators:
//   ck=colsum(Wk), cv=colsum(Wv)
//   U[e,h]=sum_d Wq[e,h*64+d]*ck[h*64+d];  a0[h]=sum_d bq[h*64+d]*ck[h*64+d]
//   G[h,j]=sum_d cv[h*64+d]*Wo[h*64+d,j];  c0[j]=sum_e bv[e]*Wo[e,j] + bo[j]
__global__ __launch_bounds__(256) void precross_k(const float* __restrict__ Wca,
                                                  const float* __restrict__ bca,
                                                  float* __restrict__ U, float* __restrict__ a0,
                                                  float* __restrict__ G, float* __restrict__ c0) {
    int n = blockIdx.x;
    const float* Wq = Wca + (size_t)n * 4 * kE * kE;
    const float* Wk = Wq + kE * kE;
    const float* Wv = Wk + kE * kE;
    const float* Wo = Wv + kE * kE;
    const float* bq = bca + n * 4 * kE;
    const float* bv = bq + 2 * kE;
    const float* bo = bq + 3 * kE;
    __shared__ float ck[kE], cv[kE];
    int tid = threadIdx.x;
    for (int j = tid; j < kE; j += 256) {
        float s1 = 0.f, s2 = 0.f;
        for (int e = 0; e < kE; ++e) { s1 += Wk[e * kE + j]; s2 += Wv[e * kE + j]; }
        ck[j] = s1; cv[j] = s2;
    }
    __syncthreads();
    for (int p = tid; p < kE * kH; p += 256) {
        int e = p >> 3, h = p & 7;
        float acc = 0.f;
        for (int d = 0; d < 64; ++d) acc = fmaf(Wq[e * kE + h * 64 + d], ck[h * 64 + d], acc);
        U[n * kE * kH + p] = acc;
    }
    if (tid < kH) {
        float acc = 0.f;
        for (int d = 0; d < 64; ++d) acc = fmaf(bq[tid * 64 + d], ck[tid * 64 + d], acc);
        a0[n * kH + tid] = acc;
    }
    for (int p = tid; p < kH * kE; p += 256) {
        int h = p >> 9, j = p & 511;
        float acc = 0.f;
        for (int d = 0; d < 64; ++d) acc = fmaf(cv[h * 64 + d], Wo[(h * 64 + d) * kE + j], acc);
        G[n * kH * kE + p] = acc;
    }
    for (int j = tid; j < kE; j += 256) {
        float acc = bo[j];
        for (int e = 0; e < kE; ++e) acc = fmaf(bv[e], Wo[e * kE + j], acc);
        c0[n * kE + j] = acc;
    }
}

// ---------------- tiled fp32 GEMM: C = A@W + bias (opt relu) ----------------
// A rows r -> (b=r/t, s=r%t), element at A[(b*kS+s)*kE + k].
// W: grouped? (matrix j/512 at W+m*kE*kE, col j%512, ld=w_ld) : W[k*w_ld + j]
// Out: C[b*out_bs + s*out_rs + j]
__global__ __launch_bounds__(256) void gemm_k(const float* __restrict__ A,
                                              const float* __restrict__ W,
                                              const float* __restrict__ bias,
                                              float* __restrict__ C, int t, int R, int ncols,
                                              int w_ld, int grouped, int relu, long out_bs,
                                              long out_rs) {
    __shared__ float As[32][33];
    __shared__ float Ws[32][68];
    const int tid = threadIdx.x;
    const int tile_j = blockIdx.x * 64;
    const int tile_r = blockIdx.y * 32;
    const float* Wt = W;
    int jbase = tile_j;
    if (grouped) { Wt = W + (size_t)(tile_j >> 9) * kE * kE; jbase = tile_j & 511; }
    const int tx = tid & 15, ty = tid >> 4;
    float acc[2][4] = {{0.f, 0.f, 0.f, 0.f}, {0.f, 0.f, 0.f, 0.f}};
    for (int k0 = 0; k0 < kE; k0 += 32) {
#pragma unroll
        for (int p = tid; p < 32 * 32; p += 256) {
            int rr = p >> 5, cc = p & 31;
            int r = tile_r + rr;
            float v = 0.f;
            if (r < R) {
                int b = r / t, s = r - b * t;
                v = A[(size_t)(b * kS + s) * kE + k0 + cc];
            }
            As[rr][cc] = v;
        }
#pragma unroll
        for (int p = tid; p < 32 * 64; p += 256) {
            int kk = p >> 6, jj = p & 63;
            float v = 0.f;
            if (tile_j + jj < ncols) v = Wt[(size_t)(k0 + kk) * w_ld + jbase + jj];
            Ws[kk][jj] = v;
        }
        __syncthreads();
#pragma unroll
        for (int kk = 0; kk < 32; ++kk) {
            float a0v = As[ty * 2 + 0][kk];
            float a1v = As[ty * 2 + 1][kk];
            const float4 wv = *reinterpret_cast<const float4*>(&Ws[kk][tx * 4]);
            acc[0][0] = fmaf(a0v, wv.x, acc[0][0]);
            acc[0][1] = fmaf(a0v, wv.y, acc[0][1]);
            acc[0][2] = fmaf(a0v, wv.z, acc[0][2]);
            acc[0][3] = fmaf(a0v, wv.w, acc[0][3]);
            acc[1][0] = fmaf(a1v, wv.x, acc[1][0]);
            acc[1][1] = fmaf(a1v, wv.y, acc[1][1]);
            acc[1][2] = fmaf(a1v, wv.z, acc[1][2]);
            acc[1][3] = fmaf(a1v, wv.w, acc[1][3]);
        }
        __syncthreads();
    }
#pragma unroll
    for (int i = 0; i < 2; ++i) {
        int r = tile_r + ty * 2 + i;
        if (r >= R) continue;
        int b = r / t, s = r - b * t;
        float* Crow = C + (size_t)b * out_bs + (size_t)s * out_rs;
#pragma unroll
        for (int q = 0; q < 4; ++q) {
            int j = tile_j + tx * 4 + q;
            if (j >= ncols) continue;
            float v = acc[i][q] + bias[j];
            if (relu) v = fmaxf(v, 0.f);
            Crow[j] = v;
        }
    }
}

// ---------------- self-attention (full, no mask), one WG per (b,h) ----------------
__global__ __launch_bounds__(256) void attn_k(const float* __restrict__ qkv,
                                              float* __restrict__ attn, int t) {
    int b = blockIdx.x >> 3, h = blockIdx.x & 7;
    __shared__ float Qs[31][65], Ks[31][65], Vs[31][65];
    __shared__ float att_s[4][32];
    for (int p = threadIdx.x; p < t * 64; p += 256) {
        int s = p >> 6, d = p & 63;
        size_t base = (size_t)(b * kS + s) * (3 * kE) + h * 64 + d;
        Qs[s][d] = qkv[base];
        Ks[s][d] = qkv[base + kE];
        Vs[s][d] = qkv[base + 2 * kE];
    }
    __syncthreads();
    int wave = threadIdx.x >> 6, lane = threadIdx.x & 63;
    for (int q = wave; q < t; q += 4) {
        float sc = -3.0e38f;
        if (lane < t) {
            float a = 0.f;
            for (int d = 0; d < 64; ++d) a = fmaf(Qs[q][d], Ks[lane][d], a);
            sc = a * 0.125f;
        }
        float m = sc;
#pragma unroll
        for (int o = 32; o > 0; o >>= 1) m = fmaxf(m, __shfl_xor(m, o));
        float e = (lane < t) ? expf(sc - m) : 0.f;
        float ssum = e;
#pragma unroll
        for (int o = 32; o > 0; o >>= 1) ssum += __shfl_xor(ssum, o);
        float a = e / ssum;
        if (lane < t) att_s[wave][lane] = a;
        float acc = 0.f;
        for (int k = 0; k < t; ++k) acc = fmaf(att_s[wave][k], Vs[k][lane], acc);
        attn[(size_t)(b * kS + q) * kE + h * 64 + lane] = acc;
    }
}

// ---------------- LayerNorm: out = LN(X + Rres) * g + b ----------------
__global__ __launch_bounds__(256) void ln_k(const float* __restrict__ X,
                                            const float* __restrict__ Rres,
                                            const float* __restrict__ gg,
                                            const float* __restrict__ bb, float* __restrict__ Out,
                                            int t) {
    __shared__ float red[4];
    int r = blockIdx.x;
    int b = r / t, s = r - b * t;
    size_t base = (size_t)(b * kS + s) * kE;
    int tid = threadIdx.x;
    float v0 = X[base + tid] + Rres[base + tid];
    float v1 = X[base + tid + 256] + Rres[base + tid + 256];
    float mean = block_reduce_sum(v0 + v1, red) * (1.f / kE);
    float d0 = v0 - mean, d1 = v1 - mean;
    float var = block_reduce_sum(d0 * d0 + d1 * d1, red) * (1.f / kE);
    float rstd = rsqrtf(var + 1e-5f);
    Out[base + tid] = fmaf(gg[tid] * d0, rstd, 0.f) + bb[tid];
    Out[base + tid + 256] = fmaf(gg[tid + 256] * d1, rstd, 0.f) + bb[tid + 256];
}

// ---------------- cross-attn reduced: alpha = Hin@U + a0; omega via softmax over w ----------------
__global__ __launch_bounds__(256) void cross_k(const float* __restrict__ Hin,
                                               const float* __restrict__ U,
                                               const float* __restrict__ a0,
                                               const float* __restrict__ w, float* __restrict__ Om,
                                               int t) {
    __shared__ float Us[kE * kH];
    __shared__ float ws[kS];
    int b = blockIdx.x, tid = threadIdx.x;
    for (int p = tid; p < kE * kH; p += 256) Us[p] = U[p];
    if (tid < t) ws[tid] = w[b * kS + tid];
    __syncthreads();
    int q = tid >> 3, h = tid & 7;
    if (q < t) {
        const float* row = Hin + (size_t)(b * kS + q) * kE;
        float acc = a0[h];
        for (int e = 0; e < kE; ++e) acc = fmaf(row[e], Us[e * kH + h], acc);
        acc *= 0.125f;  // 1/sqrt(64)
        float mm = -3.0e38f;
        for (int s = 0; s < t; ++s) mm = fmaxf(mm, acc * ws[s]);
        float se = 0.f, sw = 0.f;
        for (int s = 0; s < t; ++s) {
            float ex = expf(acc * ws[s] - mm);
            se += ex;
            sw = fmaf(ex, ws[s], sw);
        }
        Om[(size_t)(b * kS + q) * kH + h] = sw / se;
    }
}

// ---------------- cross-attn out (omega@G + c0) + residual + LN ----------------
__global__ __launch_bounds__(256) void crossout_ln_k(const float* __restrict__ Hres,
                                                     const float* __restrict__ Om,
                                                     const float* __restrict__ Gm,
                                                     const float* __restrict__ c0,
                                                     const float* __restrict__ gg,
                                                     const float* __restrict__ bb,
                                                     float* __restrict__ Out, int t) {
    __shared__ float red[4];
    __shared__ float om[kH];
    int r = blockIdx.x;
    int b = r / t, s = r - b * t;
    size_t base = (size_t)(b * kS + s) * kE;
    int tid = threadIdx.x;
    if (tid < kH) om[tid] = Om[(size_t)(b * kS + s) * kH + tid];
    __syncthreads();
    float v0 = c0[tid] + Hres[base + tid];
    float v1 = c0[tid + 256] + Hres[base + tid + 256];
#pragma unroll
    for (int h = 0; h < kH; ++h) {
        v0 = fmaf(om[h], Gm[h * kE + tid], v0);
        v1 = fmaf(om[h], Gm[h * kE + tid + 256], v1);
    }
    float mean = block_reduce_sum(v0 + v1, red) * (1.f / kE);
    float d0 = v0 - mean, d1 = v1 - mean;
    float var = block_reduce_sum(d0 * d0 + d1 * d1, red) * (1.f / kE);
    float rstd = rsqrtf(var + 1e-5f);
    Out[base + tid] = gg[tid] * d0 * rstd + bb[tid];
    Out[base + tid + 256] = gg[tid + 256] * d1 * rstd + bb[tid + 256];
}

// ---------------- softmax + argmax + emit probs + Y update, one WG per b ----------------
__global__ __launch_bounds__(256) void softargmax_k(const float* __restrict__ logits,
                                                    float* __restrict__ outp,
                                                    const float* __restrict__ emb,
                                                    const float* __restrict__ pe_t,
                                                    float* __restrict__ Y_t) {
    __shared__ float redf[4];
    __shared__ int redi[4];
    int b = blockIdx.x, tid = threadIdx.x;
    const float* lg = logits + (size_t)b * kV;
    float m = -3.4e38f;
    int mi = 0;
    for (int j = tid; j < kV; j += 256) {
        float v = lg[j];
        if (v > m) { m = v; mi = j; }
    }
#pragma unroll
    for (int o = 32; o > 0; o >>= 1) {
        float m2 = __shfl_xor(m, o);
        int i2 = __shfl_xor(mi, o);
        if (m2 > m || (m2 == m && i2 < mi)) { m = m2; mi = i2; }
    }
    int wid = tid >> 6;
    if ((tid & 63) == 0) { redf[wid] = m; redi[wid] = mi; }
    __syncthreads();
    m = redf[0]; mi = redi[0];
#pragma unroll
    for (int wv = 1; wv < 4; ++wv) {
        if (redf[wv] > m || (redf[wv] == m && redi[wv] < mi)) { m = redf[wv]; mi = redi[wv]; }
    }
    __syncthreads();
    float ssum = 0.f;
    for (int j = tid; j < kV; j += 256) ssum += expf(lg[j] - m);
    ssum = block_reduce_sum(ssum, redf);
    float inv = 1.f / ssum;
    float* orow = outp + (size_t)b * ((size_t)kS * kV);
    for (int j = tid; j < kV; j += 256) orow[j] = expf(lg[j] - m) * inv;
    const float* erow = emb + (size_t)mi * kE;
    float* yrow = Y_t + (size_t)b * (kS * kE);
    for (int j = tid; j < kE; j += 256) yrow[j] = erow[j] + pe_t[j];
}

// ---------------- host ----------------
extern "C" void kernel_launch(void* const* d_in, const int* in_sizes, int n_in, void* d_out,
                              int out_size, void* d_ws, size_t ws_size, hipStream_t stream) {
    const float* noise = (const float*)d_in[0];
    const float* W_in = (const float*)d_in[1];
    const float* b_in = (const float*)d_in[2];
    const float* emb = (const float*)d_in[3];
    const float* Wsa = (const float*)d_in[4];
    const float* bsa = (const float*)d_in[5];
    const float* Wca = (const float*)d_in[6];
    const float* bca = (const float*)d_in[7];
    const float* Wff = (const float*)d_in[8];
    const float* bff = (const float*)d_in[9];
    const float* ln_g = (const float*)d_in[10];
    const float* ln_b = (const float*)d_in[11];
    const float* softW = (const float*)d_in[12];
    const float* softb = (const float*)d_in[13];
    float* out = (float*)d_out;
    (void)d_ws; (void)ws_size; (void)in_sizes; (void)n_in; (void)out_size;

    float *w_, *pe_, *Y_, *act_, *qkv_, *attn_, *tmp_, *h_, *h2_, *ff_, *om_, *lg_, *U_, *a0_,
        *G_, *c0_;
    hipGetSymbolAddress((void**)&w_, HIP_SYMBOL(g_w));
    hipGetSymbolAddress((void**)&pe_, HIP_SYMBOL(g_pe));
    hipGetSymbolAddress((void**)&Y_, HIP_SYMBOL(g_Y));
    hipGetSymbolAddress((void**)&act_, HIP_SYMBOL(g_act));
    hipGetSymbolAddress((void**)&qkv_, HIP_SYMBOL(g_qkv));
    hipGetSymbolAddress((void**)&attn_, HIP_SYMBOL(g_attn));
    hipGetSymbolAddress((void**)&tmp_, HIP_SYMBOL(g_tmp));
    hipGetSymbolAddress((void**)&h_, HIP_SYMBOL(g_h));
    hipGetSymbolAddress((void**)&h2_, HIP_SYMBOL(g_h2));
    hipGetSymbolAddress((void**)&ff_, HIP_SYMBOL(g_ff));
    hipGetSymbolAddress((void**)&om_, HIP_SYMBOL(g_om));
    hipGetSymbolAddress((void**)&lg_, HIP_SYMBOL(g_logits));
    hipGetSymbolAddress((void**)&U_, HIP_SYMBOL(g_U));
    hipGetSymbolAddress((void**)&a0_, HIP_SYMBOL(g_a0));
    hipGetSymbolAddress((void**)&G_, HIP_SYMBOL(g_G));
    hipGetSymbolAddress((void**)&c0_, HIP_SYMBOL(g_c0));

    dim3 blk(256);
    hipLaunchKernelGGL(onehot_k, dim3((kB * kV + 255) / 256), blk, 0, stream, out);
    hipLaunchKernelGGL(pe_k, dim3(kS * kE / 256), blk, 0, stream, pe_);
    hipLaunchKernelGGL(compute_w_k, dim3(1), dim3(1024), 0, stream, noise, W_in, b_in, w_);
    hipLaunchKernelGGL(initY_k, dim3(kB * kE / 256), blk, 0, stream, emb, pe_, Y_);
    hipLaunchKernelGGL(precross_k, dim3(kNB), blk, 0, stream, Wca, bca, U_, a0_, G_, c0_);

    for (int tok = 1; tok < kS; ++tok) {
        int t = tok, R = kB * t;
        for (int n = 0; n < kNB; ++n) {
            const float* in = (n == 0) ? Y_ : act_;
            const float* Wn = Wsa + (size_t)n * 4 * kE * kE;
            const float* bn = bsa + n * 4 * kE;
            // fused QKV projection (3 E x E gemms, contiguous weights)
            hipLaunchKernelGGL(gemm_k, dim3(24, t), blk, 0, stream, in, Wn, bn, qkv_, t, R,
                               3 * kE, kE, 1, 0, (long)(kS * 3 * kE), (long)(3 * kE));
            hipLaunchKernelGGL(attn_k, dim3(kB * kH), blk, 0, stream, qkv_, attn_, t);
            hipLaunchKernelGGL(gemm_k, dim3(8, t), blk, 0, stream, attn_, Wn + 3 * kE * kE,
                               bn + 3 * kE, tmp_, t, R, kE, kE, 0, 0, (long)(kS * kE), (long)kE);
            hipLaunchKernelGGL(ln_k, dim3(R), blk, 0, stream, tmp_, in, ln_g + (n * 3) * kE,
                               ln_b + (n * 3) * kE, h_, t);
            // reduced cross-attention
            hipLaunchKernelGGL(cross_k, dim3(kB), blk, 0, stream, h_, U_ + n * kE * kH,
                               a0_ + n * kH, w_, om_, t);
            hipLaunchKernelGGL(crossout_ln_k, dim3(R), blk, 0, stream, h_, om_, G_ + n * kH * kE,
                               c0_ + n * kE, ln_g + (n * 3 + 1) * kE, ln_b + (n * 3 + 1) * kE, h2_,
                               t);
            // FF
            const float* Wf = Wff + (size_t)n * 2 * kE * kE;
            hipLaunchKernelGGL(gemm_k, dim3(8, t), blk, 0, stream, h2_, Wf, bff + n * 2 * kE, ff_,
                               t, R, kE, kE, 0, 1, (long)(kS * kE), (long)kE);
            hipLaunchKernelGGL(gemm_k, dim3(8, t), blk, 0, stream, ff_, Wf + kE * kE,
                               bff + n * 2 * kE + kE, tmp_, t, R, kE, kE, 0, 0, (long)(kS * kE),
                               (long)kE);
            hipLaunchKernelGGL(ln_k, dim3(R), blk, 0, stream, tmp_, h2_, ln_g + (n * 3 + 2) * kE,
                               ln_b + (n * 3 + 2) * kE, act_, t);
        }
        // logits for row tok-1 of final output
        hipLaunchKernelGGL(gemm_k, dim3((kV + 63) / 64, 1), blk, 0, stream,
                           act_ + (size_t)(t - 1) * kE, softW, softb, lg_, 1, kB, kV, kV, 0, 0,
                           (long)kV, 0L);
        hipLaunchKernelGGL(softargmax_k, dim3(kB), blk, 0, stream, lg_, out + (size_t)tok * kV,
                           emb, pe_ + (size_t)tok * kE, Y_ + (size_t)tok * kE);
    }
}